// Round 1
// baseline (3983.153 us; speedup 1.0000x reference)
//
#include <hip/hip_runtime.h>

#define IN_FEAT 512
#define HID 16
#define NC 7

// ---------------------------------------------------------------- degree ----
__global__ void k_deg(const int* __restrict__ dst, float* __restrict__ deg, int E) {
    int e = blockIdx.x * blockDim.x + threadIdx.x;
    if (e >= E) return;
    int d = dst[e];
    atomicAdd(&deg[d], 1.0f);
}

__global__ void k_dinv(const float* __restrict__ deg, float* __restrict__ dinv, int n) {
    int v = blockIdx.x * blockDim.x + threadIdx.x;
    if (v >= n) return;
    // +1.0f accounts for the self-loop appended by the reference
    dinv[v] = rsqrtf(deg[v] + 1.0f);
}

// ------------------------------------------------------- layer 1: x @ W1 ----
// One thread per row. 16 fp32 accumulators. x loads are float4 per-lane
// streams (lines fully consumed); W1 indices are wave-uniform -> s_load.
// Epilogue writes h1 and initializes agg1 with the self-loop message
// h1[v] * dinv[v]^2 (so the edge kernel only handles real edges).
__global__ void k_gemm1(const float* __restrict__ x, const float* __restrict__ W,
                        const float* __restrict__ dinv,
                        float* __restrict__ h1, float* __restrict__ agg1, int n) {
    int row = blockIdx.x * blockDim.x + threadIdx.x;
    if (row >= n) return;
    const float4* xr = reinterpret_cast<const float4*>(x + (size_t)row * IN_FEAT);
    float acc[HID];
#pragma unroll
    for (int c = 0; c < HID; ++c) acc[c] = 0.0f;
#pragma unroll 2
    for (int kt = 0; kt < IN_FEAT / 4; ++kt) {
        float4 xv = xr[kt];
        const float* wk = W + (size_t)kt * 4 * HID;
#pragma unroll
        for (int c = 0; c < HID; ++c) acc[c] = fmaf(xv.x, wk[c], acc[c]);
#pragma unroll
        for (int c = 0; c < HID; ++c) acc[c] = fmaf(xv.y, wk[HID + c], acc[c]);
#pragma unroll
        for (int c = 0; c < HID; ++c) acc[c] = fmaf(xv.z, wk[2 * HID + c], acc[c]);
#pragma unroll
        for (int c = 0; c < HID; ++c) acc[c] = fmaf(xv.w, wk[3 * HID + c], acc[c]);
    }
    float di = dinv[row];
    float w = di * di;
    float4* hp = reinterpret_cast<float4*>(h1 + (size_t)row * HID);
    float4* ap = reinterpret_cast<float4*>(agg1 + (size_t)row * HID);
#pragma unroll
    for (int j = 0; j < 4; ++j) {
        float4 hv = make_float4(acc[4 * j + 0], acc[4 * j + 1], acc[4 * j + 2], acc[4 * j + 3]);
        hp[j] = hv;
        ap[j] = make_float4(hv.x * w, hv.y * w, hv.z * w, hv.w * w);
    }
}

// ----------------------------------------------- layer 1 edge aggregation ---
__global__ void k_agg1(const int* __restrict__ src, const int* __restrict__ dst,
                       const float* __restrict__ dinv, const float* __restrict__ h,
                       float* __restrict__ out, int E, int n) {
    int e = blockIdx.x * blockDim.x + threadIdx.x;
    if (e >= E) return;
    int s = src[e], d = dst[e];
    if ((unsigned)s >= (unsigned)n || (unsigned)d >= (unsigned)n) return;  // safety
    float w = dinv[s] * dinv[d];
    const float4* hr = reinterpret_cast<const float4*>(h + (size_t)s * HID);
    float* o = out + (size_t)d * HID;
#pragma unroll
    for (int j = 0; j < 4; ++j) {
        float4 v = hr[j];
        atomicAdd(o + 4 * j + 0, v.x * w);
        atomicAdd(o + 4 * j + 1, v.y * w);
        atomicAdd(o + 4 * j + 2, v.z * w);
        atomicAdd(o + 4 * j + 3, v.w * w);
    }
}

// -------------------------------- layer 2: relu(agg1 + b1) @ W2, agg init ---
// h2/agg2 stored with stride 8 (slot 7 zero) for float4 alignment.
__global__ void k_layer2(const float* __restrict__ agg1, const float* __restrict__ b1,
                         const float* __restrict__ W2, const float* __restrict__ dinv,
                         float* __restrict__ h2, float* __restrict__ agg2, int n) {
    int v = blockIdx.x * blockDim.x + threadIdx.x;
    if (v >= n) return;
    const float4* ar = reinterpret_cast<const float4*>(agg1 + (size_t)v * HID);
    float t[HID];
#pragma unroll
    for (int j = 0; j < 4; ++j) {
        float4 av = ar[j];
        t[4 * j + 0] = fmaxf(av.x + b1[4 * j + 0], 0.0f);
        t[4 * j + 1] = fmaxf(av.y + b1[4 * j + 1], 0.0f);
        t[4 * j + 2] = fmaxf(av.z + b1[4 * j + 2], 0.0f);
        t[4 * j + 3] = fmaxf(av.w + b1[4 * j + 3], 0.0f);
    }
    float o[NC];
#pragma unroll
    for (int c = 0; c < NC; ++c) o[c] = 0.0f;
#pragma unroll
    for (int k = 0; k < HID; ++k) {
#pragma unroll
        for (int c = 0; c < NC; ++c) o[c] = fmaf(t[k], W2[k * NC + c], o[c]);
    }
    float di = dinv[v];
    float w = di * di;
    float* hp = h2 + (size_t)v * 8;
    float* ap = agg2 + (size_t)v * 8;
#pragma unroll
    for (int c = 0; c < NC; ++c) {
        hp[c] = o[c];
        ap[c] = o[c] * w;
    }
    hp[NC] = 0.0f;
    ap[NC] = 0.0f;
}

// ----------------------------------------------- layer 2 edge aggregation ---
__global__ void k_agg2(const int* __restrict__ src, const int* __restrict__ dst,
                       const float* __restrict__ dinv, const float* __restrict__ h,
                       float* __restrict__ out, int E, int n) {
    int e = blockIdx.x * blockDim.x + threadIdx.x;
    if (e >= E) return;
    int s = src[e], d = dst[e];
    if ((unsigned)s >= (unsigned)n || (unsigned)d >= (unsigned)n) return;  // safety
    float w = dinv[s] * dinv[d];
    const float4* hr = reinterpret_cast<const float4*>(h + (size_t)s * 8);
    float4 v0 = hr[0];
    float4 v1 = hr[1];
    float* o = out + (size_t)d * 8;
    atomicAdd(o + 0, v0.x * w);
    atomicAdd(o + 1, v0.y * w);
    atomicAdd(o + 2, v0.z * w);
    atomicAdd(o + 3, v0.w * w);
    atomicAdd(o + 4, v1.x * w);
    atomicAdd(o + 5, v1.y * w);
    atomicAdd(o + 6, v1.z * w);
}

// --------------------------------------------------- bias + log_softmax -----
__global__ void k_final(const float* __restrict__ agg2, const float* __restrict__ b2,
                        float* __restrict__ out, int n) {
    int v = blockIdx.x * blockDim.x + threadIdx.x;
    if (v >= n) return;
    float z[NC];
#pragma unroll
    for (int c = 0; c < NC; ++c) z[c] = agg2[(size_t)v * 8 + c] + b2[c];
    float m = z[0];
#pragma unroll
    for (int c = 1; c < NC; ++c) m = fmaxf(m, z[c]);
    float s = 0.0f;
#pragma unroll
    for (int c = 0; c < NC; ++c) s += expf(z[c] - m);
    float lse = logf(s) + m;
#pragma unroll
    for (int c = 0; c < NC; ++c) out[(size_t)v * NC + c] = z[c] - lse;
}

// -----------------------------------------------------------------------------
extern "C" void kernel_launch(void* const* d_in, const int* in_sizes, int n_in,
                              void* d_out, int out_size, void* d_ws, size_t ws_size,
                              hipStream_t stream) {
    const float* x  = (const float*)d_in[0];
    const int*   ei = (const int*)d_in[1];
    const float* W1 = (const float*)d_in[2];
    const float* b1 = (const float*)d_in[3];
    const float* W2 = (const float*)d_in[4];
    const float* b2 = (const float*)d_in[5];

    int n = in_sizes[0] / IN_FEAT;
    int E = in_sizes[1] / 2;
    const int* src = ei;
    const int* dst = ei + E;

    float* ws   = (float*)d_ws;
    float* deg  = ws;                        // n
    float* dinv = deg + n;                   // n
    float* h1   = dinv + n;                  // 16n
    float* agg1 = h1 + (size_t)HID * n;      // 16n
    float* h2   = agg1 + (size_t)HID * n;    // 8n
    float* agg2 = h2 + (size_t)8 * n;        // 8n

    const int tb = 256;
    int gE = (E + tb - 1) / tb;
    int gN = (n + tb - 1) / tb;

    hipMemsetAsync(deg, 0, (size_t)n * sizeof(float), stream);
    k_deg<<<gE, tb, 0, stream>>>(dst, deg, E);
    k_dinv<<<gN, tb, 0, stream>>>(deg, dinv, n);
    k_gemm1<<<gN, tb, 0, stream>>>(x, W1, dinv, h1, agg1, n);
    k_agg1<<<gE, tb, 0, stream>>>(src, dst, dinv, h1, agg1, E, n);
    k_layer2<<<gN, tb, 0, stream>>>(agg1, b1, W2, dinv, h2, agg2, n);
    k_agg2<<<gE, tb, 0, stream>>>(src, dst, dinv, h2, agg2, E, n);
    k_final<<<gN, tb, 0, stream>>>(agg2, b2, (float*)d_out, n);
}

// Round 2
// 710.642 us; speedup vs baseline: 5.6050x; 5.6050x over previous
//
#include <hip/hip_runtime.h>

#define IN_FEAT 512
#define HID 16
#define NC 7

// ------------------------------------------------- degree histogram (int) ---
__global__ void k_count(const int* __restrict__ dst, int* __restrict__ deg, int E) {
    int e = blockIdx.x * blockDim.x + threadIdx.x;
    if (e >= E) return;
    atomicAdd(&deg[dst[e]], 1);
}

__global__ void k_dinv(const int* __restrict__ deg, float* __restrict__ dinv, int n) {
    int v = blockIdx.x * blockDim.x + threadIdx.x;
    if (v >= n) return;
    // +1 accounts for the self-loop the reference appends
    dinv[v] = rsqrtf((float)deg[v] + 1.0f);
}

// ---------------------------------------- exclusive scan (single block) -----
// 1024 threads; wave shfl scan + 16-wave LDS combine; ~98 chunks for n=100k.
__global__ __launch_bounds__(1024) void k_scan(const int* __restrict__ deg,
                                               int* __restrict__ off,
                                               int* __restrict__ cur, int n) {
    __shared__ int wsum[16];
    __shared__ int s_carry;
    int tid = threadIdx.x;
    int lane = tid & 63, wid = tid >> 6;
    if (tid == 0) s_carry = 0;
    __syncthreads();
    for (int base = 0; base < n; base += 1024) {
        int i = base + tid;
        int v = (i < n) ? deg[i] : 0;
        int incl = v;
#pragma unroll
        for (int ofs = 1; ofs < 64; ofs <<= 1) {
            int t = __shfl_up(incl, ofs, 64);
            if (lane >= ofs) incl += t;
        }
        if (lane == 63) wsum[wid] = incl;
        __syncthreads();
        int wpre = 0;
        for (int k = 0; k < wid; ++k) wpre += wsum[k];
        int ex = s_carry + wpre + incl - v;
        if (i < n) { off[i] = ex; cur[i] = ex; }
        __syncthreads();
        if (tid == 1023) s_carry = ex + v;  // = old carry + chunk total
        __syncthreads();
    }
    if (tid == 0) off[n] = s_carry;
}

// ------------------------------------------------- scatter src into CSR -----
__global__ void k_scatter(const int* __restrict__ src, const int* __restrict__ dst,
                          int* __restrict__ cur, int* __restrict__ csr_src, int E) {
    int e = blockIdx.x * blockDim.x + threadIdx.x;
    if (e >= E) return;
    int s = src[e], d = dst[e];
    int pos = atomicAdd(&cur[d], 1);
    csr_src[pos] = s;
}

// ------------------------------------------------------- layer 1: x @ W1 ----
__global__ void k_gemm1(const float* __restrict__ x, const float* __restrict__ W,
                        float* __restrict__ h1, int n) {
    int row = blockIdx.x * blockDim.x + threadIdx.x;
    if (row >= n) return;
    const float4* xr = reinterpret_cast<const float4*>(x + (size_t)row * IN_FEAT);
    float acc[HID];
#pragma unroll
    for (int c = 0; c < HID; ++c) acc[c] = 0.0f;
#pragma unroll 2
    for (int kt = 0; kt < IN_FEAT / 4; ++kt) {
        float4 xv = xr[kt];
        const float* wk = W + (size_t)kt * 4 * HID;
#pragma unroll
        for (int c = 0; c < HID; ++c) acc[c] = fmaf(xv.x, wk[c], acc[c]);
#pragma unroll
        for (int c = 0; c < HID; ++c) acc[c] = fmaf(xv.y, wk[HID + c], acc[c]);
#pragma unroll
        for (int c = 0; c < HID; ++c) acc[c] = fmaf(xv.z, wk[2 * HID + c], acc[c]);
#pragma unroll
        for (int c = 0; c < HID; ++c) acc[c] = fmaf(xv.w, wk[3 * HID + c], acc[c]);
    }
    float4* hp = reinterpret_cast<float4*>(h1 + (size_t)row * HID);
#pragma unroll
    for (int j = 0; j < 4; ++j)
        hp[j] = make_float4(acc[4 * j], acc[4 * j + 1], acc[4 * j + 2], acc[4 * j + 3]);
}

// ------------------- gather layer 1 + bias + relu + @W2 (fused, 4 lanes/v) --
__global__ void k_gather1(const float* __restrict__ h1, const int* __restrict__ csr_src,
                          const int* __restrict__ off, const float* __restrict__ dinv,
                          const float* __restrict__ b1, const float* __restrict__ W2,
                          float* __restrict__ h2, int n) {
    int t = blockIdx.x * blockDim.x + threadIdx.x;
    int v = t >> 2, part = t & 3;
    if (v >= n) return;
    float di = dinv[v];
    float4 hv = reinterpret_cast<const float4*>(h1 + (size_t)v * HID)[part];
    float dw = di * di;
    float4 acc = make_float4(hv.x * dw, hv.y * dw, hv.z * dw, hv.w * dw);
    int beg = off[v], end = off[v + 1];
    for (int i = beg; i < end; ++i) {
        int s = csr_src[i];
        float w = dinv[s] * di;
        float4 hs = reinterpret_cast<const float4*>(h1 + (size_t)s * HID)[part];
        acc.x = fmaf(hs.x, w, acc.x);
        acc.y = fmaf(hs.y, w, acc.y);
        acc.z = fmaf(hs.z, w, acc.z);
        acc.w = fmaf(hs.w, w, acc.w);
    }
    float tt[4];
    tt[0] = fmaxf(acc.x + b1[part * 4 + 0], 0.0f);
    tt[1] = fmaxf(acc.y + b1[part * 4 + 1], 0.0f);
    tt[2] = fmaxf(acc.z + b1[part * 4 + 2], 0.0f);
    tt[3] = fmaxf(acc.w + b1[part * 4 + 3], 0.0f);
    float o[NC];
#pragma unroll
    for (int c = 0; c < NC; ++c) o[c] = 0.0f;
#pragma unroll
    for (int j = 0; j < 4; ++j) {
        int k = part * 4 + j;
#pragma unroll
        for (int c = 0; c < NC; ++c) o[c] = fmaf(tt[j], W2[k * NC + c], o[c]);
    }
    // reduce partial o across the 4 lanes of this node's group
#pragma unroll
    for (int c = 0; c < NC; ++c) {
        o[c] += __shfl_xor(o[c], 1);
        o[c] += __shfl_xor(o[c], 2);
    }
    float4* hp = reinterpret_cast<float4*>(h2 + (size_t)v * 8);
    if (part == 0) hp[0] = make_float4(o[0], o[1], o[2], o[3]);
    if (part == 1) hp[1] = make_float4(o[4], o[5], o[6], 0.0f);
}

// ------------------- gather layer 2 + bias + log_softmax (fused, 1 th/v) ----
__global__ void k_gather2(const float* __restrict__ h2, const int* __restrict__ csr_src,
                          const int* __restrict__ off, const float* __restrict__ dinv,
                          const float* __restrict__ b2, float* __restrict__ out, int n) {
    int v = blockIdx.x * blockDim.x + threadIdx.x;
    if (v >= n) return;
    float di = dinv[v];
    float dw = di * di;
    const float4* hr = reinterpret_cast<const float4*>(h2 + (size_t)v * 8);
    float4 s0 = hr[0], s1 = hr[1];
    float4 a0 = make_float4(s0.x * dw, s0.y * dw, s0.z * dw, s0.w * dw);
    float4 a1 = make_float4(s1.x * dw, s1.y * dw, s1.z * dw, 0.0f);
    int beg = off[v], end = off[v + 1];
    for (int i = beg; i < end; ++i) {
        int s = csr_src[i];
        float w = dinv[s] * di;
        const float4* hs = reinterpret_cast<const float4*>(h2 + (size_t)s * 8);
        float4 v0 = hs[0], v1 = hs[1];
        a0.x = fmaf(v0.x, w, a0.x);
        a0.y = fmaf(v0.y, w, a0.y);
        a0.z = fmaf(v0.z, w, a0.z);
        a0.w = fmaf(v0.w, w, a0.w);
        a1.x = fmaf(v1.x, w, a1.x);
        a1.y = fmaf(v1.y, w, a1.y);
        a1.z = fmaf(v1.z, w, a1.z);
    }
    float z[NC];
    z[0] = a0.x + b2[0]; z[1] = a0.y + b2[1]; z[2] = a0.z + b2[2]; z[3] = a0.w + b2[3];
    z[4] = a1.x + b2[4]; z[5] = a1.y + b2[5]; z[6] = a1.z + b2[6];
    float m = z[0];
#pragma unroll
    for (int c = 1; c < NC; ++c) m = fmaxf(m, z[c]);
    float sum = 0.0f;
#pragma unroll
    for (int c = 0; c < NC; ++c) sum += expf(z[c] - m);
    float lse = logf(sum) + m;
#pragma unroll
    for (int c = 0; c < NC; ++c) out[(size_t)v * NC + c] = z[c] - lse;
}

// -----------------------------------------------------------------------------
extern "C" void kernel_launch(void* const* d_in, const int* in_sizes, int n_in,
                              void* d_out, int out_size, void* d_ws, size_t ws_size,
                              hipStream_t stream) {
    const float* x  = (const float*)d_in[0];
    const int*   ei = (const int*)d_in[1];
    const float* W1 = (const float*)d_in[2];
    const float* b1 = (const float*)d_in[3];
    const float* W2 = (const float*)d_in[4];
    const float* b2 = (const float*)d_in[5];

    int n = in_sizes[0] / IN_FEAT;
    int E = in_sizes[1] / 2;
    const int* src = ei;
    const int* dst = ei + E;

    // workspace layout (16B-aligned chunks first)
    char* p = (char*)d_ws;
    float* h1      = (float*)p;                 p += (size_t)HID * n * sizeof(float); // 6.4 MB
    float* h2      = (float*)p;                 p += (size_t)8 * n * sizeof(float);   // 3.2 MB
    int*   csr_src = (int*)p;                   p += (size_t)E * sizeof(int);         // 12.8 MB
    int*   deg     = (int*)p;                   p += (size_t)n * sizeof(int);
    int*   off     = (int*)p;                   p += (size_t)(n + 1) * sizeof(int);
    int*   cur     = (int*)p;                   p += (size_t)n * sizeof(int);
    float* dinv    = (float*)p;                 p += (size_t)n * sizeof(float);

    const int tb = 256;
    int gE = (E + tb - 1) / tb;
    int gN = (n + tb - 1) / tb;
    int gN4 = (4 * n + tb - 1) / tb;

    hipMemsetAsync(deg, 0, (size_t)n * sizeof(int), stream);
    k_count  <<<gE,  tb, 0, stream>>>(dst, deg, E);
    k_dinv   <<<gN,  tb, 0, stream>>>(deg, dinv, n);
    k_scan   <<<1, 1024, 0, stream>>>(deg, off, cur, n);
    k_scatter<<<gE,  tb, 0, stream>>>(src, dst, cur, csr_src, E);
    k_gemm1  <<<gN,  tb, 0, stream>>>(x, W1, h1, n);
    k_gather1<<<gN4, tb, 0, stream>>>(h1, csr_src, off, dinv, b1, W2, h2, n);
    k_gather2<<<gN,  tb, 0, stream>>>(h2, csr_src, off, dinv, b2, (float*)d_out, n);
}

// Round 3
// 583.146 us; speedup vs baseline: 6.8304x; 1.2186x over previous
//
#include <hip/hip_runtime.h>

#define IN_FEAT 512
#define HID 16
#define NC 7
#define NXCD 8
#define SC_EPT 16  // edges per thread in scatter

// ------------------------------------------------- degree histogram (int) ---
__global__ void k_count(const int* __restrict__ dst, int* __restrict__ deg, int E) {
    int e = blockIdx.x * blockDim.x + threadIdx.x;
    if (e >= E) return;
    atomicAdd(&deg[dst[e]], 1);
}

// ----------------------- exclusive scan (single block) + dinv fused ---------
// 1024 threads; wave shfl scan + 16-wave LDS combine; ~98 chunks for n=100k.
__global__ __launch_bounds__(1024) void k_scan(const int* __restrict__ deg,
                                               int* __restrict__ off,
                                               int* __restrict__ cur,
                                               float* __restrict__ dinv, int n) {
    __shared__ int wsum[16];
    __shared__ int s_carry;
    int tid = threadIdx.x;
    int lane = tid & 63, wid = tid >> 6;
    if (tid == 0) s_carry = 0;
    __syncthreads();
    for (int base = 0; base < n; base += 1024) {
        int i = base + tid;
        int v = (i < n) ? deg[i] : 0;
        int incl = v;
#pragma unroll
        for (int ofs = 1; ofs < 64; ofs <<= 1) {
            int t = __shfl_up(incl, ofs, 64);
            if (lane >= ofs) incl += t;
        }
        if (lane == 63) wsum[wid] = incl;
        __syncthreads();
        int wpre = 0;
        for (int k = 0; k < wid; ++k) wpre += wsum[k];
        int ex = s_carry + wpre + incl - v;
        if (i < n) {
            off[i] = ex;
            cur[i] = ex;
            dinv[i] = rsqrtf((float)v + 1.0f);  // +1 = self-loop
        }
        __syncthreads();
        if (tid == 1023) s_carry = ex + v;  // = old carry + chunk total
        __syncthreads();
    }
    if (tid == 0) off[n] = s_carry;
}

// -------------------------------- scatter src into CSR, XCD-affine ranges ---
// Block b: edge-chunk b>>3, dst-range b&7. Workgroups round-robin across the
// 8 XCDs, so all writers of a CSR range share one L2 -> full-line writebacks.
__global__ void k_scatter(const int* __restrict__ src, const int* __restrict__ dst,
                          int* __restrict__ cur, int* __restrict__ csr_src,
                          int E, int n) {
    int chunk = blockIdx.x >> 3;
    int range = blockIdx.x & (NXCD - 1);
    int rsz = (n + NXCD - 1) / NXCD;
    int lo = range * rsz;
    int hi = min(n, lo + rsz);
    int base = chunk * (blockDim.x * SC_EPT) + threadIdx.x;
#pragma unroll
    for (int i = 0; i < SC_EPT; ++i) {
        int e = base + i * blockDim.x;
        if (e >= E) break;  // e monotone in i per-thread
        int d = dst[e];
        if (d >= lo && d < hi) {
            int pos = atomicAdd(&cur[d], 1);
            csr_src[pos] = src[e];
        }
    }
}

// ------------------------------------------------------- layer 1: x @ W1 ----
__global__ void k_gemm1(const float* __restrict__ x, const float* __restrict__ W,
                        float* __restrict__ h1, int n) {
    int row = blockIdx.x * blockDim.x + threadIdx.x;
    if (row >= n) return;
    const float4* xr = reinterpret_cast<const float4*>(x + (size_t)row * IN_FEAT);
    float acc[HID];
#pragma unroll
    for (int c = 0; c < HID; ++c) acc[c] = 0.0f;
#pragma unroll 2
    for (int kt = 0; kt < IN_FEAT / 4; ++kt) {
        float4 xv = xr[kt];
        const float* wk = W + (size_t)kt * 4 * HID;
#pragma unroll
        for (int c = 0; c < HID; ++c) acc[c] = fmaf(xv.x, wk[c], acc[c]);
#pragma unroll
        for (int c = 0; c < HID; ++c) acc[c] = fmaf(xv.y, wk[HID + c], acc[c]);
#pragma unroll
        for (int c = 0; c < HID; ++c) acc[c] = fmaf(xv.z, wk[2 * HID + c], acc[c]);
#pragma unroll
        for (int c = 0; c < HID; ++c) acc[c] = fmaf(xv.w, wk[3 * HID + c], acc[c]);
    }
    float4* hp = reinterpret_cast<float4*>(h1 + (size_t)row * HID);
#pragma unroll
    for (int j = 0; j < 4; ++j)
        hp[j] = make_float4(acc[4 * j], acc[4 * j + 1], acc[4 * j + 2], acc[4 * j + 3]);
}

// ------------------- gather layer 1 + bias + relu + @W2 (fused, 4 lanes/v) --
__global__ void k_gather1(const float* __restrict__ h1, const int* __restrict__ csr_src,
                          const int* __restrict__ off, const float* __restrict__ dinv,
                          const float* __restrict__ b1, const float* __restrict__ W2,
                          float* __restrict__ h2, int n) {
    int t = blockIdx.x * blockDim.x + threadIdx.x;
    int v = t >> 2, part = t & 3;
    if (v >= n) return;
    float di = dinv[v];
    float4 hv = reinterpret_cast<const float4*>(h1 + (size_t)v * HID)[part];
    float dw = di * di;
    float4 acc = make_float4(hv.x * dw, hv.y * dw, hv.z * dw, hv.w * dw);
    int beg = off[v], end = off[v + 1];
    for (int i = beg; i < end; ++i) {
        int s = csr_src[i];
        float w = dinv[s] * di;
        float4 hs = reinterpret_cast<const float4*>(h1 + (size_t)s * HID)[part];
        acc.x = fmaf(hs.x, w, acc.x);
        acc.y = fmaf(hs.y, w, acc.y);
        acc.z = fmaf(hs.z, w, acc.z);
        acc.w = fmaf(hs.w, w, acc.w);
    }
    float tt[4];
    tt[0] = fmaxf(acc.x + b1[part * 4 + 0], 0.0f);
    tt[1] = fmaxf(acc.y + b1[part * 4 + 1], 0.0f);
    tt[2] = fmaxf(acc.z + b1[part * 4 + 2], 0.0f);
    tt[3] = fmaxf(acc.w + b1[part * 4 + 3], 0.0f);
    float o[NC];
#pragma unroll
    for (int c = 0; c < NC; ++c) o[c] = 0.0f;
#pragma unroll
    for (int j = 0; j < 4; ++j) {
        int k = part * 4 + j;
#pragma unroll
        for (int c = 0; c < NC; ++c) o[c] = fmaf(tt[j], W2[k * NC + c], o[c]);
    }
#pragma unroll
    for (int c = 0; c < NC; ++c) {
        o[c] += __shfl_xor(o[c], 1);
        o[c] += __shfl_xor(o[c], 2);
    }
    float4* hp = reinterpret_cast<float4*>(h2 + (size_t)v * 8);
    if (part == 0) hp[0] = make_float4(o[0], o[1], o[2], o[3]);
    if (part == 1) hp[1] = make_float4(o[4], o[5], o[6], 0.0f);
}

// ------------------- gather layer 2 + bias + log_softmax (fused, 1 th/v) ----
__global__ void k_gather2(const float* __restrict__ h2, const int* __restrict__ csr_src,
                          const int* __restrict__ off, const float* __restrict__ dinv,
                          const float* __restrict__ b2, float* __restrict__ out, int n) {
    int v = blockIdx.x * blockDim.x + threadIdx.x;
    if (v >= n) return;
    float di = dinv[v];
    float dw = di * di;
    const float4* hr = reinterpret_cast<const float4*>(h2 + (size_t)v * 8);
    float4 s0 = hr[0], s1 = hr[1];
    float4 a0 = make_float4(s0.x * dw, s0.y * dw, s0.z * dw, s0.w * dw);
    float4 a1 = make_float4(s1.x * dw, s1.y * dw, s1.z * dw, 0.0f);
    int beg = off[v], end = off[v + 1];
    for (int i = beg; i < end; ++i) {
        int s = csr_src[i];
        float w = dinv[s] * di;
        const float4* hs = reinterpret_cast<const float4*>(h2 + (size_t)s * 8);
        float4 v0 = hs[0], v1 = hs[1];
        a0.x = fmaf(v0.x, w, a0.x);
        a0.y = fmaf(v0.y, w, a0.y);
        a0.z = fmaf(v0.z, w, a0.z);
        a0.w = fmaf(v0.w, w, a0.w);
        a1.x = fmaf(v1.x, w, a1.x);
        a1.y = fmaf(v1.y, w, a1.y);
        a1.z = fmaf(v1.z, w, a1.z);
    }
    float z[NC];
    z[0] = a0.x + b2[0]; z[1] = a0.y + b2[1]; z[2] = a0.z + b2[2]; z[3] = a0.w + b2[3];
    z[4] = a1.x + b2[4]; z[5] = a1.y + b2[5]; z[6] = a1.z + b2[6];
    float m = z[0];
#pragma unroll
    for (int c = 1; c < NC; ++c) m = fmaxf(m, z[c]);
    float sum = 0.0f;
#pragma unroll
    for (int c = 0; c < NC; ++c) sum += expf(z[c] - m);
    float lse = logf(sum) + m;
#pragma unroll
    for (int c = 0; c < NC; ++c) out[(size_t)v * NC + c] = z[c] - lse;
}

// -----------------------------------------------------------------------------
extern "C" void kernel_launch(void* const* d_in, const int* in_sizes, int n_in,
                              void* d_out, int out_size, void* d_ws, size_t ws_size,
                              hipStream_t stream) {
    const float* x  = (const float*)d_in[0];
    const int*   ei = (const int*)d_in[1];
    const float* W1 = (const float*)d_in[2];
    const float* b1 = (const float*)d_in[3];
    const float* W2 = (const float*)d_in[4];
    const float* b2 = (const float*)d_in[5];

    int n = in_sizes[0] / IN_FEAT;
    int E = in_sizes[1] / 2;
    const int* src = ei;
    const int* dst = ei + E;

    // workspace layout (16B-aligned chunks first)
    char* p = (char*)d_ws;
    float* h1      = (float*)p;                 p += (size_t)HID * n * sizeof(float); // 6.4 MB
    float* h2      = (float*)p;                 p += (size_t)8 * n * sizeof(float);   // 3.2 MB
    int*   csr_src = (int*)p;                   p += (size_t)E * sizeof(int);         // 12.8 MB
    int*   deg     = (int*)p;                   p += (size_t)n * sizeof(int);
    int*   off     = (int*)p;                   p += (size_t)(n + 1) * sizeof(int);
    int*   cur     = (int*)p;                   p += (size_t)n * sizeof(int);
    float* dinv    = (float*)p;                 p += (size_t)n * sizeof(float);

    const int tb = 256;
    int gE = (E + tb - 1) / tb;
    int gN = (n + tb - 1) / tb;
    int gN4 = (4 * n + tb - 1) / tb;
    int nchunk = (E + tb * SC_EPT - 1) / (tb * SC_EPT);

    hipMemsetAsync(deg, 0, (size_t)n * sizeof(int), stream);
    k_count  <<<gE,  tb, 0, stream>>>(dst, deg, E);
    k_scan   <<<1, 1024, 0, stream>>>(deg, off, cur, dinv, n);
    k_scatter<<<nchunk * NXCD, tb, 0, stream>>>(src, dst, cur, csr_src, E, n);
    k_gemm1  <<<gN,  tb, 0, stream>>>(x, W1, h1, n);
    k_gather1<<<gN4, tb, 0, stream>>>(h1, csr_src, off, dinv, b1, W2, h2, n);
    k_gather2<<<gN,  tb, 0, stream>>>(h2, csr_src, off, dinv, b2, (float*)d_out, n);
}